// Round 4
// baseline (25102.328 us; speedup 1.0000x reference)
//
#include <hip/hip_runtime.h>
#include <math.h>

#define HID   512
#define SEQL  256
#define BATCH 2048
#define NCLS  10
#define NB    16      // batch cols per WG -> one MFMA n-tile
#define NKB   17      // 16 k-blocks of h + 1 augmented block [x;1;0...]
#define NWG   (BATCH / NB)   // 128 workgroups

typedef __attribute__((ext_vector_type(8))) short          short8;
typedef __attribute__((ext_vector_type(4))) unsigned short ushort4v;
typedef __attribute__((ext_vector_type(4))) float          f32x4;

static __device__ __forceinline__ unsigned short f2bf(float f) {
    unsigned u = __builtin_bit_cast(unsigned, f);
    unsigned r = (u + 0x7FFFu + ((u >> 16) & 1u)) >> 16;   // RNE
    return (unsigned short)r;
}
static __device__ __forceinline__ float bf2f(unsigned short h) {
    unsigned u = ((unsigned)h) << 16;
    return __builtin_bit_cast(float, u);
}
static __device__ __forceinline__ float sigm(float v) {
    return __builtin_amdgcn_rcpf(1.f + __expf(-v));
}
static __device__ __forceinline__ float tanh_fast(float v) {
    return fmaf(-2.f, __builtin_amdgcn_rcpf(1.f + __expf(2.f * v)), 1.f);
}

// ---------------------------------------------------------------------------
// Pack weights into MFMA A-fragment order, bf16. Layout (shorts):
//   Apre[(((mt*NKB + kb)*4 + g)*64 + lane)*8 + j8]
//     = W[g][mt*16 + (lane&15)][kb*32 + (lane>>4)*8 + j8]
// mt in [0,32) = hidden-row tile-in-gate, g = gate. kb==16 is the augmented
// block: k=512 -> wx[g][row], k=513 -> bias[g][row], else 0.
// Total 32*17*4 KB = 2.176 MB (L2-resident). Per (wave,q) slice of the main
// kernel the 68 frags (kb x g) are 68 KB CONTIGUOUS -> ideal L2 stream.
// ---------------------------------------------------------------------------
__global__ void build_A(const float* __restrict__ wgh, const float* __restrict__ wih,
                        const float* __restrict__ wfh, const float* __restrict__ woh,
                        const float* __restrict__ wgx, const float* __restrict__ wix,
                        const float* __restrict__ wfx, const float* __restrict__ wox,
                        const float* __restrict__ bg,  const float* __restrict__ bi,
                        const float* __restrict__ bf_, const float* __restrict__ bo,
                        unsigned short* __restrict__ Apre)
{
    const int kb   = blockIdx.x;          // 0..16
    const int mt   = blockIdx.y;          // 0..31
    const int g    = blockIdx.z;          // 0..3
    const int lane = threadIdx.x;         // 0..63
    const int j    = mt * 16 + (lane & 15);
    const int quad = lane >> 4;

    const float* W[4]  = {wgh, wih, wfh, woh};
    const float* Wx[4] = {wgx, wix, wfx, wox};
    const float* Bs[4] = {bg,  bi,  bf_, bo};

    unsigned short tmp[8];
    #pragma unroll
    for (int j8 = 0; j8 < 8; j8++) {
        const int k = kb * 32 + quad * 8 + j8;
        float v;
        if (kb < 16) {
            v = W[g][j * HID + k];
        } else {
            const int kk = k - HID;
            v = (kk == 0) ? Wx[g][j] : (kk == 1) ? Bs[g][j] : 0.f;
        }
        tmp[j8] = f2bf(v);
    }
    short8* dst = (short8*)(Apre + ((((size_t)mt * NKB + kb) * 4 + g) * 64 + lane) * 8);
    *dst = *(const short8*)tmp;
}

// ---------------------------------------------------------------------------
// Persistent MFMA LSTM, 128 WGs x 512 threads, NB=16 cols each (1 WG/CU on
// 128 CUs). Wave w owns h-rows [w*64, w*64+64): 4 q-groups x 4 gates of
// 16x16 m-tiles. B (h) kept in 17 reg fragments; A streamed from L2.
// Only 16 acc VGPRs live at a time (q-grouped) -> no spills at 256 budget.
// ---------------------------------------------------------------------------
__global__ __launch_bounds__(512) void lstm_mfma(
    const float* __restrict__ x,                 // [B][SEQ]
    const unsigned short* __restrict__ Apre,
    const float* __restrict__ wph, const float* __restrict__ bp,
    const float* __restrict__ h_init, const float* __restrict__ c_init,
    float* __restrict__ out)                     // [B][C]
{
    __shared__ unsigned short hB[16 * 512];       // 16 KB: h in B-frag order
    __shared__ unsigned short x_s[SEQL * NB];     // 8 KB: x bf16 [t][col]

    const int tid  = threadIdx.x;
    const int wave = tid >> 6;
    const int lane = tid & 63;
    const int col  = lane & 15;
    const int quad = lane >> 4;
    const int b0   = blockIdx.x * NB;

    // x slice -> LDS bf16, [t][c] (coalesced global reads along t)
    for (int i = tid; i < SEQL * NB; i += 512) {
        const int c = i >> 8, t = i & 255;
        x_s[t * NB + c] = f2bf(x[(b0 + c) * SEQL + t]);
    }
    // h_init broadcast in B-fragment order
    for (int i = tid; i < 16 * 512; i += 512) {
        const int kb = i >> 9, l = (i >> 3) & 63, j8 = i & 7;
        hB[i] = f2bf(h_init[kb * 32 + ((l >> 4) << 3) + j8]);
    }

    float c_reg[4][4];
    #pragma unroll
    for (int q = 0; q < 4; q++)
        #pragma unroll
        for (int r = 0; r < 4; r++)
            c_reg[q][r] = c_init[wave * 64 + q * 16 + quad * 4 + r];
    __syncthreads();

    for (int t = 0; t < SEQL; t++) {
        // (A) load all B fragments for this step into registers
        short8 Bf[NKB];
        #pragma unroll
        for (int kb = 0; kb < 16; kb++)
            Bf[kb] = *(const short8*)(hB + kb * 512 + lane * 8);
        {
            short8 bx = 0;
            if (quad == 0) {
                bx[0] = (short)x_s[t * NB + col];
                bx[1] = (short)0x3F80;   // 1.0 bf16
            }
            Bf[16] = bx;
        }
        __syncthreads();   // B in regs everywhere; hB free for step t+1 writes

        // (C) q-grouped accumulation + fused pointwise
        #pragma unroll
        for (int q = 0; q < 4; q++) {
            const unsigned short* Aq =
                Apre + (size_t)(wave * 4 + q) * (NKB * 4 * 512) + lane * 8;
            f32x4 acc0 = {0,0,0,0}, acc1 = {0,0,0,0}, acc2 = {0,0,0,0}, acc3 = {0,0,0,0};
            #pragma unroll
            for (int kb = 0; kb < NKB; kb++) {
                const short8 a0 = *(const short8*)(Aq + (size_t)kb * 2048 + 0 * 512);
                const short8 a1 = *(const short8*)(Aq + (size_t)kb * 2048 + 1 * 512);
                const short8 a2 = *(const short8*)(Aq + (size_t)kb * 2048 + 2 * 512);
                const short8 a3 = *(const short8*)(Aq + (size_t)kb * 2048 + 3 * 512);
                acc0 = __builtin_amdgcn_mfma_f32_16x16x32_bf16(a0, Bf[kb], acc0, 0, 0, 0);
                acc1 = __builtin_amdgcn_mfma_f32_16x16x32_bf16(a1, Bf[kb], acc1, 0, 0, 0);
                acc2 = __builtin_amdgcn_mfma_f32_16x16x32_bf16(a2, Bf[kb], acc2, 0, 0, 0);
                acc3 = __builtin_amdgcn_mfma_f32_16x16x32_bf16(a3, Bf[kb], acc3, 0, 0, 0);
            }
            // pointwise for this q-group's 4 rows (per lane), col = lane&15
            ushort4v pk;
            #pragma unroll
            for (int r = 0; r < 4; r++) {
                const float g_ = tanh_fast(acc0[r]);
                const float ii = sigm(acc1[r]);
                const float ff = sigm(acc2[r]);
                const float oo = sigm(acc3[r]);
                const float cc = fmaf(c_reg[q][r], ff, g_ * ii);
                c_reg[q][r] = cc;
                pk[r] = f2bf(tanh_fast(cc) * oo);
            }
            const int j0 = wave * 64 + q * 16 + quad * 4;
            *(ushort4v*)(hB + (j0 >> 5) * 512 + (((j0 >> 3) & 3) * 16 + col) * 8 + (j0 & 7)) = pk;
        }
        __syncthreads();   // hB complete for step t+1
    }

    // epilogue: out[b][cls] = bp[cls] + sum_k wph[cls][k] * h[k][b]
    if (tid < NB * NCLS) {
        const int c = tid / NCLS, cls = tid % NCLS;
        float s = bp[cls];
        for (int k = 0; k < HID; k++) {
            const unsigned short hv =
                hB[(k >> 5) * 512 + (((k >> 3) & 3) * 16 + c) * 8 + (k & 7)];
            s = fmaf(wph[cls * HID + k], bf2f(hv), s);
        }
        out[(b0 + c) * NCLS + cls] = s;
    }
}

extern "C" void kernel_launch(void* const* d_in, const int* in_sizes, int n_in,
                              void* d_out, int out_size, void* d_ws, size_t ws_size,
                              hipStream_t stream)
{
    const float* x   = (const float*)d_in[0];
    const float* wgx = (const float*)d_in[1];
    const float* wix = (const float*)d_in[2];
    const float* wfx = (const float*)d_in[3];
    const float* wox = (const float*)d_in[4];
    const float* wgh = (const float*)d_in[5];
    const float* wih = (const float*)d_in[6];
    const float* wfh = (const float*)d_in[7];
    const float* woh = (const float*)d_in[8];
    const float* bg  = (const float*)d_in[9];
    const float* bi  = (const float*)d_in[10];
    const float* bf  = (const float*)d_in[11];
    const float* bo  = (const float*)d_in[12];
    const float* wph = (const float*)d_in[13];
    const float* bp  = (const float*)d_in[14];
    const float* h0  = (const float*)d_in[15];
    const float* c0  = (const float*)d_in[16];
    float* out = (float*)d_out;
    unsigned short* Apre = (unsigned short*)d_ws;   // 32*17*4*64*8*2 B = 2.176 MiB

    build_A<<<dim3(NKB, 32, 4), dim3(64), 0, stream>>>(
        wgh, wih, wfh, woh, wgx, wix, wfx, wox, bg, bi, bf, bo, Apre);
    lstm_mfma<<<dim3(NWG), dim3(512), 0, stream>>>(
        x, Apre, wph, bp, h0, c0, out);
}